// Round 3
// baseline (377.719 us; speedup 1.0000x reference)
//
#include <hip/hip_runtime.h>

// fc_out[b,o] = concat_gap[b,:]·weight[o,:] + bias[o]              (16x3)
// vis_i[b,0,s] = sum_c out_i[b,c,s] * 0.5*(weight[0,c+off]+weight[1,c+off])
// Output flat f32: fc(48) | vis1(983040) | vis2(131072) | vis3(16384)
//
// f4-unit shapes: out1 [16][64][15360], out2 [16][128][2048], out3 [16][256][256]
// Traffic floor: 335 MB read + 4.5 MB write -> ~52 us @ 6.3 TB/s.
//
// v3: long-contiguous-run design. Channel dim is split ACROSS blocks so each
// block reads long forward-sequential runs; channel-group partials go to d_ws
// (plain cached stores -> L2/IC-resident), tiny pass-2 kernel reduces them.
//   pass1 grid (1121 blocks):
//     [0,128)     vis2: b x chunk(2) x cgroup(4): 32 planes x 16KB runs, 512KB/blk
//     [128,160)   vis3: b x cgroup(2): 128 planes fully sequential, 512KB/blk
//     [160,1120)  vis1: b x chunk(15) x cgroup(4): 16 planes x 16KB runs, 256KB/blk
//     1120        fc
//   pass2 grid (1104 blocks): sum 4 (vis1/vis2) or 2 (vis3) partials -> d_out
//
// ws layout (f4): vis1 [0,983040) = [b][chunk15][cg4][1024]
//                 vis2 [983040,1114112) = [b][chunk2][cg4][1024]
//                 vis3 [1114112,1122304) = [b][cg2][256]     (~18 MB total)

typedef float fvec4 __attribute__((ext_vector_type(4)));

#define W2_OFF 983040
#define W3_OFF 1114112

__device__ __forceinline__ fvec4 ntload(const fvec4* p) {
    return __builtin_nontemporal_load(p);
}
__device__ __forceinline__ void ntstore(fvec4* p, fvec4 v) {
    __builtin_nontemporal_store(v, p);
}

__global__ __launch_bounds__(256) void pass1_partials(
    const float* __restrict__ concat_gap,
    const float* __restrict__ out1,
    const float* __restrict__ out2,
    const float* __restrict__ out3,
    const float* __restrict__ weight,
    const float* __restrict__ bias,
    float* __restrict__ d_out,
    fvec4* __restrict__ ws)
{
    const int t = threadIdx.x;
    const int blk = blockIdx.x;
    __shared__ float s_w[128];

    if (blk < 128) {
        // ---- vis2: 32 planes (cgroup) x 1024-f4 spatial chunk; 16KB runs @32KB stride
        const int b = blk >> 3, r = blk & 7, chunk = r >> 2, cg = r & 3;
        if (t < 32) {
            const int c = cg * 32 + t;
            s_w[t] = 0.5f * (weight[64 + c] + weight[512 + c]);
        }
        __syncthreads();
        const fvec4* in = (const fvec4*)out2
            + (size_t)(b * 128 + cg * 32) * 2048 + chunk * 1024 + t;
        fvec4 a0 = {0,0,0,0}, a1 = {0,0,0,0}, a2 = {0,0,0,0}, a3 = {0,0,0,0};
        #pragma unroll 4
        for (int cc = 0; cc < 32; ++cc) {
            const float w = s_w[cc];
            const fvec4* p = in + (size_t)cc * 2048;
            a0 += ntload(p)       * w;
            a1 += ntload(p + 256) * w;
            a2 += ntload(p + 512) * w;
            a3 += ntload(p + 768) * w;
        }
        fvec4* o = ws + W2_OFF + (size_t)((b * 2 + chunk) * 4 + cg) * 1024 + t;
        o[0] = a0; o[256] = a1; o[512] = a2; o[768] = a3;
    } else if (blk < 160) {
        // ---- vis3: 128 consecutive planes, block streams 512KB fully sequential
        const int id = blk - 128;
        const int b = id >> 1, cg = id & 1;
        if (t < 128) {
            const int c = cg * 128 + t;
            s_w[t] = 0.5f * (weight[192 + c] + weight[640 + c]);
        }
        __syncthreads();
        const fvec4* in = (const fvec4*)out3 + (size_t)(b * 256 + cg * 128) * 256 + t;
        fvec4 acc = {0,0,0,0};
        #pragma unroll 8
        for (int cc = 0; cc < 128; ++cc)
            acc += ntload(in + (size_t)cc * 256) * s_w[cc];
        ws[W3_OFF + (b * 2 + cg) * 256 + t] = acc;
    } else if (blk < 1120) {
        // ---- vis1: 16 planes (cgroup) x 1024-f4 chunk; 16KB runs @240KB stride
        const int id = blk - 160;
        const int b = id / 60, r = id % 60, chunk = r >> 2, cg = r & 3;
        float wr[16];
        #pragma unroll
        for (int j = 0; j < 16; ++j) {
            const int c = cg * 16 + j;
            wr[j] = 0.5f * (weight[c] + weight[448 + c]);
        }
        const fvec4* in = (const fvec4*)out1
            + (size_t)(b * 64 + cg * 16) * 15360 + chunk * 1024 + t;
        fvec4 a0 = {0,0,0,0}, a1 = {0,0,0,0}, a2 = {0,0,0,0}, a3 = {0,0,0,0};
        #pragma unroll 4
        for (int cc = 0; cc < 16; ++cc) {
            const float w = wr[cc];
            const fvec4* p = in + (size_t)cc * 15360;
            a0 += ntload(p)       * w;
            a1 += ntload(p + 256) * w;
            a2 += ntload(p + 512) * w;
            a3 += ntload(p + 768) * w;
        }
        fvec4* o = ws + (size_t)((b * 15 + chunk) * 4 + cg) * 1024 + t;
        o[0] = a0; o[256] = a1; o[512] = a2; o[768] = a3;
    } else {
        // ---- fc: 16x3 addmm
        if (t < 48) {
            const int b = t / 3, o = t % 3;
            const float* g = concat_gap + b * 448;
            const float* w = weight + o * 448;
            float s = 0.f;
            #pragma unroll 8
            for (int k = 0; k < 448; ++k) s += g[k] * w[k];
            d_out[t] = s + bias[o];
        }
    }
}

__global__ __launch_bounds__(256) void pass2_reduce(
    const fvec4* __restrict__ ws,
    float* __restrict__ d_out)
{
    const int gid = blockIdx.x * 256 + threadIdx.x;   // [0, 282624) f4s
    fvec4* o4 = (fvec4*)d_out;
    if (gid < 245760) {
        // vis1: [b][15360] f4, 4 partials
        const int b = gid / 15360, within = gid % 15360;
        const int chunk = within >> 10, s = within & 1023;
        const fvec4* p = ws + (size_t)(b * 15 + chunk) * 4096 + s;
        ntstore(o4 + 12 + gid, p[0] + p[1024] + p[2048] + p[3072]);
    } else if (gid < 278528) {
        // vis2: [b][2048] f4, 4 partials
        const int g2 = gid - 245760;
        const int b = g2 >> 11, within = g2 & 2047;
        const int chunk = within >> 10, s = within & 1023;
        const fvec4* p = ws + W2_OFF + (size_t)(b * 2 + chunk) * 4096 + s;
        ntstore(o4 + 245772 + g2, p[0] + p[1024] + p[2048] + p[3072]);
    } else {
        // vis3: [b][256] f4, 2 partials
        const int g3 = gid - 278528;
        const int b = g3 >> 8, s = g3 & 255;
        const fvec4* p = ws + W3_OFF + b * 512 + s;
        ntstore(o4 + 278540 + g3, p[0] + p[256]);
    }
}

extern "C" void kernel_launch(void* const* d_in, const int* in_sizes, int n_in,
                              void* d_out, int out_size, void* d_ws, size_t ws_size,
                              hipStream_t stream) {
    pass1_partials<<<1121, 256, 0, stream>>>(
        (const float*)d_in[0], (const float*)d_in[1], (const float*)d_in[2],
        (const float*)d_in[3], (const float*)d_in[4], (const float*)d_in[5],
        (float*)d_out, (fvec4*)d_ws);
    pass2_reduce<<<1104, 256, 0, stream>>>((const fvec4*)d_ws, (float*)d_out);
}